// Round 1
// baseline (299.488 us; speedup 1.0000x reference)
//
#include <hip/hip_runtime.h>
#include <hip/hip_bf16.h>
#include <stdint.h>

// Sizes fixed by the problem.
#define BB   8
#define NN_  1024
#define CC   768
#define HH   12
#define HDD  64
// M = B*N = 8192 rows of x; QKV out cols = 2304.

typedef __attribute__((ext_vector_type(8))) short bf16x8;   // 8 bf16 (4 VGPRs) — guide §3
typedef __attribute__((ext_vector_type(4))) float f32x4;    // MFMA accumulator
typedef __attribute__((ext_vector_type(4))) float f32x4v;
typedef __attribute__((ext_vector_type(4))) unsigned short u16x4;

__device__ __forceinline__ unsigned short f2bf(float f) {
    union { float f; unsigned int u; } v; v.f = f;
    unsigned int r = v.u + 0x7fffu + ((v.u >> 16) & 1u);   // RNE
    return (unsigned short)(r >> 16);
}

// ---------------------------------------------------------------- converts
__global__ void cvt4_f32_bf16(const f32x4v* __restrict__ in,
                              u16x4* __restrict__ out, int n4) {
    int i = blockIdx.x * blockDim.x + threadIdx.x;
    int stride = gridDim.x * blockDim.x;
    for (; i < n4; i += stride) {
        f32x4v v = in[i];
        u16x4 o;
        o.x = f2bf(v.x); o.y = f2bf(v.y); o.z = f2bf(v.z); o.w = f2bf(v.w);
        out[i] = o;
    }
}

// ---------------------------------------------------------------- QKV GEMM
// C[8192,2304] = A[8192,768] * Bt[2304,768]^T, bf16 in, fp32 acc.
// Epilogue scatters: part0 -> Rq = relu(q), part1 -> Rk = relu(k),
// part2 -> VT[b,h,d,n] = 4*relu(v) (transposed for PV fragment loads).
__global__ __launch_bounds__(256)
void qkv_gemm(const unsigned short* __restrict__ A,
              const unsigned short* __restrict__ Bt,
              unsigned short* __restrict__ Rq,
              unsigned short* __restrict__ Rk,
              unsigned short* __restrict__ VT) {
    __shared__ short sA[128 * 32];
    __shared__ short sB[128 * 32];
    const int K = 768;
    const int lane = threadIdx.x & 63;
    const int wid  = threadIdx.x >> 6;
    const int wr = wid >> 1, wc = wid & 1;
    const int brow = blockIdx.x * 128;
    const int bcol = blockIdx.y * 128;
    const int t = threadIdx.x;

    f32x4 acc[4][4];
#pragma unroll
    for (int m = 0; m < 4; m++)
#pragma unroll
        for (int n = 0; n < 4; n++) acc[m][n] = (f32x4){0.f, 0.f, 0.f, 0.f};

    for (int k0 = 0; k0 < K; k0 += 32) {
#pragma unroll
        for (int i = 0; i < 2; i++) {
            int tt  = i * 256 + t;          // 0..511
            int row = tt >> 2;
            int kc  = (tt & 3) * 8;
            const unsigned short* ga = A  + (size_t)(brow + row) * K + k0 + kc;
            const unsigned short* gb = Bt + (size_t)(bcol + row) * K + k0 + kc;
            short* la = &sA[(i * 256 + wid * 64) * 8];   // wave-uniform base
            short* lb = &sB[(i * 256 + wid * 64) * 8];
            __builtin_amdgcn_global_load_lds((const __attribute__((address_space(1))) void*)ga,
                                             (__attribute__((address_space(3))) void*)la, 16, 0, 0);
            __builtin_amdgcn_global_load_lds((const __attribute__((address_space(1))) void*)gb,
                                             (__attribute__((address_space(3))) void*)lb, 16, 0, 0);
        }
        __syncthreads();
        bf16x8 af[4], bfg[4];
#pragma unroll
        for (int m = 0; m < 4; m++) {
            int r = wr * 64 + m * 16 + (lane & 15);
            af[m] = *(const bf16x8*)&sA[r * 32 + (lane >> 4) * 8];
        }
#pragma unroll
        for (int n = 0; n < 4; n++) {
            int c = wc * 64 + n * 16 + (lane & 15);
            bfg[n] = *(const bf16x8*)&sB[c * 32 + (lane >> 4) * 8];
        }
#pragma unroll
        for (int m = 0; m < 4; m++)
#pragma unroll
            for (int n = 0; n < 4; n++)
                acc[m][n] = __builtin_amdgcn_mfma_f32_16x16x32_bf16(af[m], bfg[n], acc[m][n], 0, 0, 0);
        __syncthreads();
    }

    // epilogue: wave-constant part/head/batch (64-aligned tiles never cross boundaries)
    const int colbase = bcol + wc * 64;
    const int p  = colbase / 768;
    const int hh = (colbase - p * 768) >> 6;
    const int rowbase = brow + wr * 64;
    const int bb = rowbase >> 10;
    const size_t qk_base = ((size_t)(bb * HH + hh)) * NN_ * HDD;
    const size_t vt_base = ((size_t)(bb * HH + hh)) * HDD * NN_;
#pragma unroll
    for (int m = 0; m < 4; m++) {
        int nn = (rowbase + m * 16 + (lane >> 4) * 4) & (NN_ - 1);
#pragma unroll
        for (int n = 0; n < 4; n++) {
            int dd = n * 16 + (lane & 15);
#pragma unroll
            for (int r = 0; r < 4; r++) {
                float rl = fmaxf(acc[m][n][r], 0.f);
                if (p == 0)      Rq[qk_base + (size_t)(nn + r) * HDD + dd] = f2bf(rl);
                else if (p == 1) Rk[qk_base + (size_t)(nn + r) * HDD + dd] = f2bf(rl);
                else             VT[vt_base + (size_t)dd * NN_ + (nn + r)] = f2bf(4.f * rl);
            }
        }
    }
}

// ---------------------------------------------------------------- spk FC
// In-place: R[98304,64] <- bf16( R @ W^T + bias ).  W bf16 [64,64], bias fp32.
__global__ __launch_bounds__(256)
void spk_kernel(unsigned short* __restrict__ R,
                const unsigned short* __restrict__ W,
                const float* __restrict__ bias) {
    const int lane = threadIdx.x & 63;
    const int wid  = threadIdx.x >> 6;
    const int rowbase = blockIdx.x * 64 + wid * 16;
    const unsigned short* Arow = R + (size_t)(rowbase + (lane & 15)) * 64 + (lane >> 4) * 8;
    bf16x8 a0 = *(const bf16x8*)Arow;
    bf16x8 a1 = *(const bf16x8*)(Arow + 32);
    f32x4 acc[4];
#pragma unroll
    for (int n = 0; n < 4; n++) {
        acc[n] = (f32x4){0.f, 0.f, 0.f, 0.f};
        const unsigned short* Wrow = W + (size_t)(n * 16 + (lane & 15)) * 64 + (lane >> 4) * 8;
        bf16x8 b0 = *(const bf16x8*)Wrow;
        bf16x8 b1 = *(const bf16x8*)(Wrow + 32);
        acc[n] = __builtin_amdgcn_mfma_f32_16x16x32_bf16(a0, b0, acc[n], 0, 0, 0);
        acc[n] = __builtin_amdgcn_mfma_f32_16x16x32_bf16(a1, b1, acc[n], 0, 0, 0);
    }
#pragma unroll
    for (int n = 0; n < 4; n++) {
        int col = n * 16 + (lane & 15);
        float bv = bias[col];
#pragma unroll
        for (int r = 0; r < 4; r++) {
            int row = rowbase + (lane >> 4) * 4 + r;
            R[(size_t)row * 64 + col] = f2bf(acc[n][r] + bv);
        }
    }
}

// ---------------------------------------------------------------- attention
// att = softmax(0.25*relu(Q K^T)) ; out = att @ V.  No max-subtraction needed:
// logits in [0, ~0.1]; relu-then-exp means S<=0 contributes exactly 1.0.
__global__ __launch_bounds__(256)
void attn_kernel(const unsigned short* __restrict__ Q,
                 const unsigned short* __restrict__ Kx,
                 const unsigned short* __restrict__ VT,
                 unsigned short* __restrict__ AO) {
    __shared__ __align__(16) short Plds[4][16][72];   // +8 pad: b128 reads spread banks
    const int lane = threadIdx.x & 63;
    const int wid  = threadIdx.x >> 6;
    const int bh = blockIdx.x >> 4;    // 0..95
    const int qt = blockIdx.x & 15;
    const int b = bh / HH, h = bh - b * HH;
    const unsigned short* Qs = Q  + (size_t)bh * NN_ * HDD;
    const unsigned short* Ks = Kx + (size_t)bh * NN_ * HDD;
    const unsigned short* Vt = VT + (size_t)bh * HDD * NN_;
    const int qrow0 = qt * 64 + wid * 16;

    bf16x8 a0 = *(const bf16x8*)&Qs[(size_t)(qrow0 + (lane & 15)) * HDD + (lane >> 4) * 8];
    bf16x8 a1 = *(const bf16x8*)&Qs[(size_t)(qrow0 + (lane & 15)) * HDD + 32 + (lane >> 4) * 8];

    f32x4 accO[4];
#pragma unroll
    for (int n = 0; n < 4; n++) accO[n] = (f32x4){0.f, 0.f, 0.f, 0.f};
    float sump[4] = {0.f, 0.f, 0.f, 0.f};

    for (int kt = 0; kt < NN_ / 64; ++kt) {
        f32x4 S[4];
#pragma unroll
        for (int n = 0; n < 4; n++) {
            S[n] = (f32x4){0.f, 0.f, 0.f, 0.f};
            int key = kt * 64 + n * 16 + (lane & 15);
            const unsigned short* kr = &Ks[(size_t)key * HDD + (lane >> 4) * 8];
            bf16x8 b0 = *(const bf16x8*)kr;
            bf16x8 b1 = *(const bf16x8*)(kr + 32);
            S[n] = __builtin_amdgcn_mfma_f32_16x16x32_bf16(a0, b0, S[n], 0, 0, 0);
            S[n] = __builtin_amdgcn_mfma_f32_16x16x32_bf16(a1, b1, S[n], 0, 0, 0);
        }
#pragma unroll
        for (int n = 0; n < 4; n++)
#pragma unroll
            for (int r = 0; r < 4; r++) {
                float pv = __expf(0.25f * fmaxf(S[n][r], 0.f));
                sump[r] += pv;
                Plds[wid][(lane >> 4) * 4 + r][n * 16 + (lane & 15)] = (short)f2bf(pv);
            }
        __syncthreads();   // drains lgkm: per-wave P writes visible to own reads
        bf16x8 pa0 = *(const bf16x8*)&Plds[wid][lane & 15][(lane >> 4) * 8];
        bf16x8 pa1 = *(const bf16x8*)&Plds[wid][lane & 15][32 + (lane >> 4) * 8];
#pragma unroll
        for (int n = 0; n < 4; n++) {
            int d = n * 16 + (lane & 15);
            const unsigned short* vr = &Vt[(size_t)d * NN_ + kt * 64 + (lane >> 4) * 8];
            bf16x8 v0 = *(const bf16x8*)vr;
            bf16x8 v1 = *(const bf16x8*)(vr + 32);
            accO[n] = __builtin_amdgcn_mfma_f32_16x16x32_bf16(pa0, v0, accO[n], 0, 0, 0);
            accO[n] = __builtin_amdgcn_mfma_f32_16x16x32_bf16(pa1, v1, accO[n], 0, 0, 0);
        }
    }
    // row-sum reduce across the 16 key-lanes (row = (lane>>4)*4 + r is shared by lane&15 group)
#pragma unroll
    for (int r = 0; r < 4; r++) {
        float s = sump[r];
        s += __shfl_xor(s, 1, 64);
        s += __shfl_xor(s, 2, 64);
        s += __shfl_xor(s, 4, 64);
        s += __shfl_xor(s, 8, 64);
        sump[r] = 1.f / s;
    }
#pragma unroll
    for (int n = 0; n < 4; n++) {
        int d = n * 16 + (lane & 15);
#pragma unroll
        for (int r = 0; r < 4; r++) {
            int qrow = qrow0 + (lane >> 4) * 4 + r;
            AO[((size_t)(b * NN_ + qrow)) * CC + h * HDD + d] = f2bf(accO[n][r] * sump[r]);
        }
    }
}

// ---------------------------------------------------------------- proj GEMM
// Out[8192,768] = A[8192,768] * Bt[768,768]^T + bias  (fp32 out)
__global__ __launch_bounds__(256)
void proj_gemm(const unsigned short* __restrict__ A,
               const unsigned short* __restrict__ Bt,
               const float* __restrict__ bias,
               float* __restrict__ Out) {
    __shared__ short sA[128 * 32];
    __shared__ short sB[128 * 32];
    const int K = 768;
    const int lane = threadIdx.x & 63;
    const int wid  = threadIdx.x >> 6;
    const int wr = wid >> 1, wc = wid & 1;
    const int brow = blockIdx.x * 128;
    const int bcol = blockIdx.y * 128;
    const int t = threadIdx.x;

    f32x4 acc[4][4];
#pragma unroll
    for (int m = 0; m < 4; m++)
#pragma unroll
        for (int n = 0; n < 4; n++) acc[m][n] = (f32x4){0.f, 0.f, 0.f, 0.f};

    for (int k0 = 0; k0 < K; k0 += 32) {
#pragma unroll
        for (int i = 0; i < 2; i++) {
            int tt  = i * 256 + t;
            int row = tt >> 2;
            int kc  = (tt & 3) * 8;
            const unsigned short* ga = A  + (size_t)(brow + row) * K + k0 + kc;
            const unsigned short* gb = Bt + (size_t)(bcol + row) * K + k0 + kc;
            short* la = &sA[(i * 256 + wid * 64) * 8];
            short* lb = &sB[(i * 256 + wid * 64) * 8];
            __builtin_amdgcn_global_load_lds((const __attribute__((address_space(1))) void*)ga,
                                             (__attribute__((address_space(3))) void*)la, 16, 0, 0);
            __builtin_amdgcn_global_load_lds((const __attribute__((address_space(1))) void*)gb,
                                             (__attribute__((address_space(3))) void*)lb, 16, 0, 0);
        }
        __syncthreads();
        bf16x8 af[4], bfg[4];
#pragma unroll
        for (int m = 0; m < 4; m++) {
            int r = wr * 64 + m * 16 + (lane & 15);
            af[m] = *(const bf16x8*)&sA[r * 32 + (lane >> 4) * 8];
        }
#pragma unroll
        for (int n = 0; n < 4; n++) {
            int c = wc * 64 + n * 16 + (lane & 15);
            bfg[n] = *(const bf16x8*)&sB[c * 32 + (lane >> 4) * 8];
        }
#pragma unroll
        for (int m = 0; m < 4; m++)
#pragma unroll
            for (int n = 0; n < 4; n++)
                acc[m][n] = __builtin_amdgcn_mfma_f32_16x16x32_bf16(af[m], bfg[n], acc[m][n], 0, 0, 0);
        __syncthreads();
    }
#pragma unroll
    for (int m = 0; m < 4; m++)
#pragma unroll
        for (int n = 0; n < 4; n++) {
            int col = bcol + wc * 64 + n * 16 + (lane & 15);
            float bv = bias[col];
#pragma unroll
            for (int r = 0; r < 4; r++) {
                int row = brow + wr * 64 + m * 16 + (lane >> 4) * 4 + r;
                Out[(size_t)row * 768 + col] = acc[m][n][r] + bv;
            }
        }
}

// ---------------------------------------------------------------- launcher
extern "C" void kernel_launch(void* const* d_in, const int* in_sizes, int n_in,
                              void* d_out, int out_size, void* d_ws, size_t ws_size,
                              hipStream_t stream) {
    const float* x     = (const float*)d_in[0];
    const float* Wqkv  = (const float*)d_in[1];
    const float* Wfc1  = (const float*)d_in[2];
    const float* bfc1  = (const float*)d_in[3];
    const float* Wfc2  = (const float*)d_in[4];
    const float* bfc2  = (const float*)d_in[5];
    const float* Wproj = (const float*)d_in[6];
    const float* bproj = (const float*)d_in[7];
    float* out = (float*)d_out;

    char* ws = (char*)d_ws;
    const size_t SZ_XN = (size_t)8192 * 768 * 2;                 // 12.58 MB
    unsigned short* x_bf    = (unsigned short*)ws; ws += SZ_XN;  // reused as attn_out
    unsigned short* wqkv_bf = (unsigned short*)ws; ws += (size_t)2304 * 768 * 2;
    unsigned short* wproj_bf= (unsigned short*)ws; ws += (size_t)768 * 768 * 2;
    unsigned short* wfc1_bf = (unsigned short*)ws; ws += 64 * 64 * 2;
    unsigned short* wfc2_bf = (unsigned short*)ws; ws += 64 * 64 * 2;
    unsigned short* Rq      = (unsigned short*)ws; ws += SZ_XN;  // -> Q_spk (in place)
    unsigned short* Rk      = (unsigned short*)ws; ws += SZ_XN;  // -> K_spk (in place)
    unsigned short* VT      = (unsigned short*)ws; ws += SZ_XN;  // V_rec transposed [b,h,d,n]

    cvt4_f32_bf16<<<2048, 256, 0, stream>>>((const f32x4v*)x,     (u16x4*)x_bf,     8192 * 768 / 4);
    cvt4_f32_bf16<<<1024, 256, 0, stream>>>((const f32x4v*)Wqkv,  (u16x4*)wqkv_bf,  2304 * 768 / 4);
    cvt4_f32_bf16<<<576,  256, 0, stream>>>((const f32x4v*)Wproj, (u16x4*)wproj_bf, 768 * 768 / 4);
    cvt4_f32_bf16<<<4,    256, 0, stream>>>((const f32x4v*)Wfc1,  (u16x4*)wfc1_bf,  64 * 64 / 4);
    cvt4_f32_bf16<<<4,    256, 0, stream>>>((const f32x4v*)Wfc2,  (u16x4*)wfc2_bf,  64 * 64 / 4);

    qkv_gemm<<<dim3(64, 18), 256, 0, stream>>>(x_bf, wqkv_bf, Rq, Rk, VT);
    spk_kernel<<<1536, 256, 0, stream>>>(Rq, wfc1_bf, bfc1);
    spk_kernel<<<1536, 256, 0, stream>>>(Rk, wfc2_bf, bfc2);
    attn_kernel<<<1536, 256, 0, stream>>>(Rq, Rk, VT, x_bf);
    proj_gemm<<<dim3(64, 6), 256, 0, stream>>>(x_bf, wproj_bf, bproj, out);
}

// Round 2
// 285.456 us; speedup vs baseline: 1.0492x; 1.0492x over previous
//
#include <hip/hip_runtime.h>
#include <hip/hip_bf16.h>
#include <stdint.h>

// Sizes fixed by the problem.
#define BB   8
#define NN_  1024
#define CC   768
#define HH   12
#define HDD  64

typedef __attribute__((ext_vector_type(8))) short bf16x8;   // 8 bf16 (4 VGPRs)
typedef __attribute__((ext_vector_type(4))) float f32x4;    // MFMA accumulator
typedef __attribute__((ext_vector_type(4))) float f32x4v;
typedef __attribute__((ext_vector_type(4))) unsigned short u16x4;

__device__ __forceinline__ unsigned short f2bf(float f) {
    union { float f; unsigned int u; } v; v.f = f;
    unsigned int r = v.u + 0x7fffu + ((v.u >> 16) & 1u);   // RNE
    return (unsigned short)(r >> 16);
}

// ---------------------------------------------------------------- converts
__global__ void cvt4_f32_bf16(const f32x4v* __restrict__ in,
                              u16x4* __restrict__ out, int n4) {
    int i = blockIdx.x * blockDim.x + threadIdx.x;
    int stride = gridDim.x * blockDim.x;
    for (; i < n4; i += stride) {
        f32x4v v = in[i];
        u16x4 o;
        o.x = f2bf(v.x); o.y = f2bf(v.y); o.z = f2bf(v.z); o.w = f2bf(v.w);
        out[i] = o;
    }
}

// ---------------------------------------------------------------- QKV GEMM
__global__ __launch_bounds__(256)
void qkv_gemm(const unsigned short* __restrict__ A,
              const unsigned short* __restrict__ Bt,
              unsigned short* __restrict__ Rq,
              unsigned short* __restrict__ Rk,
              unsigned short* __restrict__ VT) {
    __shared__ short sA[128 * 32];
    __shared__ short sB[128 * 32];
    const int K = 768;
    const int lane = threadIdx.x & 63;
    const int wid  = threadIdx.x >> 6;
    const int wr = wid >> 1, wc = wid & 1;
    const int brow = blockIdx.x * 128;
    const int bcol = blockIdx.y * 128;
    const int t = threadIdx.x;

    f32x4 acc[4][4];
#pragma unroll
    for (int m = 0; m < 4; m++)
#pragma unroll
        for (int n = 0; n < 4; n++) acc[m][n] = (f32x4){0.f, 0.f, 0.f, 0.f};

    for (int k0 = 0; k0 < K; k0 += 32) {
#pragma unroll
        for (int i = 0; i < 2; i++) {
            int tt  = i * 256 + t;          // 0..511
            int row = tt >> 2;
            int kc  = (tt & 3) * 8;
            const unsigned short* ga = A  + (size_t)(brow + row) * K + k0 + kc;
            const unsigned short* gb = Bt + (size_t)(bcol + row) * K + k0 + kc;
            short* la = &sA[(i * 256 + wid * 64) * 8];   // wave-uniform base
            short* lb = &sB[(i * 256 + wid * 64) * 8];
            __builtin_amdgcn_global_load_lds((const __attribute__((address_space(1))) void*)ga,
                                             (__attribute__((address_space(3))) void*)la, 16, 0, 0);
            __builtin_amdgcn_global_load_lds((const __attribute__((address_space(1))) void*)gb,
                                             (__attribute__((address_space(3))) void*)lb, 16, 0, 0);
        }
        __syncthreads();
        bf16x8 af[4], bfg[4];
#pragma unroll
        for (int m = 0; m < 4; m++) {
            int r = wr * 64 + m * 16 + (lane & 15);
            af[m] = *(const bf16x8*)&sA[r * 32 + (lane >> 4) * 8];
        }
#pragma unroll
        for (int n = 0; n < 4; n++) {
            int c = wc * 64 + n * 16 + (lane & 15);
            bfg[n] = *(const bf16x8*)&sB[c * 32 + (lane >> 4) * 8];
        }
#pragma unroll
        for (int m = 0; m < 4; m++)
#pragma unroll
            for (int n = 0; n < 4; n++)
                acc[m][n] = __builtin_amdgcn_mfma_f32_16x16x32_bf16(af[m], bfg[n], acc[m][n], 0, 0, 0);
        __syncthreads();
    }

    const int colbase = bcol + wc * 64;
    const int p  = colbase / 768;
    const int hh = (colbase - p * 768) >> 6;
    const int rowbase = brow + wr * 64;
    const int bb = rowbase >> 10;
    const size_t qk_base = ((size_t)(bb * HH + hh)) * NN_ * HDD;
    const size_t vt_base = ((size_t)(bb * HH + hh)) * HDD * NN_;
#pragma unroll
    for (int m = 0; m < 4; m++) {
        int nn = (rowbase + m * 16 + (lane >> 4) * 4) & (NN_ - 1);
#pragma unroll
        for (int n = 0; n < 4; n++) {
            int dd = n * 16 + (lane & 15);
#pragma unroll
            for (int r = 0; r < 4; r++) {
                float rl = fmaxf(acc[m][n][r], 0.f);
                if (p == 0)      Rq[qk_base + (size_t)(nn + r) * HDD + dd] = f2bf(rl);
                else if (p == 1) Rk[qk_base + (size_t)(nn + r) * HDD + dd] = f2bf(rl);
                else             VT[vt_base + (size_t)dd * NN_ + (nn + r)] = f2bf(4.f * rl);
            }
        }
    }
}

// ---------------------------------------------------------------- spk FC
__global__ __launch_bounds__(256)
void spk_kernel(unsigned short* __restrict__ R,
                const unsigned short* __restrict__ W,
                const float* __restrict__ bias) {
    const int lane = threadIdx.x & 63;
    const int wid  = threadIdx.x >> 6;
    const int rowbase = blockIdx.x * 64 + wid * 16;
    const unsigned short* Arow = R + (size_t)(rowbase + (lane & 15)) * 64 + (lane >> 4) * 8;
    bf16x8 a0 = *(const bf16x8*)Arow;
    bf16x8 a1 = *(const bf16x8*)(Arow + 32);
    f32x4 acc[4];
#pragma unroll
    for (int n = 0; n < 4; n++) {
        acc[n] = (f32x4){0.f, 0.f, 0.f, 0.f};
        const unsigned short* Wrow = W + (size_t)(n * 16 + (lane & 15)) * 64 + (lane >> 4) * 8;
        bf16x8 b0 = *(const bf16x8*)Wrow;
        bf16x8 b1 = *(const bf16x8*)(Wrow + 32);
        acc[n] = __builtin_amdgcn_mfma_f32_16x16x32_bf16(a0, b0, acc[n], 0, 0, 0);
        acc[n] = __builtin_amdgcn_mfma_f32_16x16x32_bf16(a1, b1, acc[n], 0, 0, 0);
    }
#pragma unroll
    for (int n = 0; n < 4; n++) {
        int col = n * 16 + (lane & 15);
        float bv = bias[col];
#pragma unroll
        for (int r = 0; r < 4; r++) {
            int row = rowbase + (lane >> 4) * 4 + r;
            R[(size_t)row * 64 + col] = f2bf(acc[n][r] + bv);
        }
    }
}

// ---------------------------------------------------------------- attention
// att = softmax(0.25*relu(Q K^T)) ; out = att @ V.  Logits in [0,~0.1] => no
// max-subtraction. Waves are fully independent: Plds is wave-private, so the
// P round-trip needs only a per-wave lgkmcnt(0) wait, NOT __syncthreads.
// Register double-buffer for K fragments (next kt prefetched during current),
// V fragments issued at top of the iteration (hide under S-MFMA + softmax).
__global__ __launch_bounds__(256, 2)
void attn_kernel(const unsigned short* __restrict__ Q,
                 const unsigned short* __restrict__ Kx,
                 const unsigned short* __restrict__ VT,
                 unsigned short* __restrict__ AO) {
    __shared__ __align__(16) short Plds[4][16][72];   // wave-private [wid]
    const int lane = threadIdx.x & 63;
    const int wid  = threadIdx.x >> 6;
    const int lo = lane & 15, hi = lane >> 4;
    const int bh = blockIdx.x >> 4;    // 0..95
    const int qt = blockIdx.x & 15;
    const int b = bh / HH, h = bh - b * HH;
    const unsigned short* Qs = Q  + (size_t)bh * NN_ * HDD;
    const unsigned short* Ks = Kx + (size_t)bh * NN_ * HDD;
    const unsigned short* Vt = VT + (size_t)bh * HDD * NN_;
    const int qrow0 = qt * 64 + wid * 16;

    bf16x8 a0 = *(const bf16x8*)&Qs[(size_t)(qrow0 + lo) * HDD + hi * 8];
    bf16x8 a1 = *(const bf16x8*)&Qs[(size_t)(qrow0 + lo) * HDD + 32 + hi * 8];

    f32x4 accO[4];
#pragma unroll
    for (int n = 0; n < 4; n++) accO[n] = (f32x4){0.f, 0.f, 0.f, 0.f};
    float sump[4] = {0.f, 0.f, 0.f, 0.f};

    bf16x8 kA0,kA1,kA2,kA3,kA4,kA5,kA6,kA7;
    bf16x8 kB0,kB1,kB2,kB3,kB4,kB5,kB6,kB7;
    bf16x8 vv0,vv1,vv2,vv3,vv4,vv5,vv6,vv7;

#define LOADK(K0,K1,K2,K3,K4,K5,K6,K7, kt_) do {                              \
    const unsigned short* kp_ = Ks + (size_t)((kt_) * 64 + lo) * HDD + hi * 8;\
    K0 = *(const bf16x8*)(kp_);                                               \
    K1 = *(const bf16x8*)(kp_ + 32);                                          \
    K2 = *(const bf16x8*)(kp_ + 16 * HDD);                                    \
    K3 = *(const bf16x8*)(kp_ + 16 * HDD + 32);                               \
    K4 = *(const bf16x8*)(kp_ + 32 * HDD);                                    \
    K5 = *(const bf16x8*)(kp_ + 32 * HDD + 32);                               \
    K6 = *(const bf16x8*)(kp_ + 48 * HDD);                                    \
    K7 = *(const bf16x8*)(kp_ + 48 * HDD + 32);                               \
} while (0)

#define LOADV(kt_) do {                                                       \
    const unsigned short* vp_ = Vt + (size_t)lo * NN_ + (kt_) * 64 + hi * 8;  \
    vv0 = *(const bf16x8*)(vp_);                                              \
    vv1 = *(const bf16x8*)(vp_ + 32);                                         \
    vv2 = *(const bf16x8*)(vp_ + 16 * NN_);                                   \
    vv3 = *(const bf16x8*)(vp_ + 16 * NN_ + 32);                              \
    vv4 = *(const bf16x8*)(vp_ + 32 * NN_);                                   \
    vv5 = *(const bf16x8*)(vp_ + 32 * NN_ + 32);                              \
    vv6 = *(const bf16x8*)(vp_ + 48 * NN_);                                   \
    vv7 = *(const bf16x8*)(vp_ + 48 * NN_ + 32);                              \
} while (0)

#define BODY(KC0,KC1,KC2,KC3,KC4,KC5,KC6,KC7,                                 \
             KN0,KN1,KN2,KN3,KN4,KN5,KN6,KN7, kt_) do {                       \
    LOADV(kt_);                                                               \
    if ((kt_) + 1 < 16) LOADK(KN0,KN1,KN2,KN3,KN4,KN5,KN6,KN7, (kt_) + 1);    \
    f32x4 S0 = (f32x4){0,0,0,0}, S1 = (f32x4){0,0,0,0};                       \
    f32x4 S2 = (f32x4){0,0,0,0}, S3 = (f32x4){0,0,0,0};                       \
    S0 = __builtin_amdgcn_mfma_f32_16x16x32_bf16(a0, KC0, S0, 0, 0, 0);       \
    S0 = __builtin_amdgcn_mfma_f32_16x16x32_bf16(a1, KC1, S0, 0, 0, 0);       \
    S1 = __builtin_amdgcn_mfma_f32_16x16x32_bf16(a0, KC2, S1, 0, 0, 0);       \
    S1 = __builtin_amdgcn_mfma_f32_16x16x32_bf16(a1, KC3, S1, 0, 0, 0);       \
    S2 = __builtin_amdgcn_mfma_f32_16x16x32_bf16(a0, KC4, S2, 0, 0, 0);       \
    S2 = __builtin_amdgcn_mfma_f32_16x16x32_bf16(a1, KC5, S2, 0, 0, 0);       \
    S3 = __builtin_amdgcn_mfma_f32_16x16x32_bf16(a0, KC6, S3, 0, 0, 0);       \
    S3 = __builtin_amdgcn_mfma_f32_16x16x32_bf16(a1, KC7, S3, 0, 0, 0);       \
    _Pragma("unroll")                                                         \
    for (int r = 0; r < 4; r++) {                                             \
        float p0 = __expf(0.25f * fmaxf(S0[r], 0.f));                         \
        float p1 = __expf(0.25f * fmaxf(S1[r], 0.f));                         \
        float p2 = __expf(0.25f * fmaxf(S2[r], 0.f));                         \
        float p3 = __expf(0.25f * fmaxf(S3[r], 0.f));                         \
        sump[r] += (p0 + p1) + (p2 + p3);                                     \
        Plds[wid][hi * 4 + r][lo]      = (short)f2bf(p0);                     \
        Plds[wid][hi * 4 + r][16 + lo] = (short)f2bf(p1);                     \
        Plds[wid][hi * 4 + r][32 + lo] = (short)f2bf(p2);                     \
        Plds[wid][hi * 4 + r][48 + lo] = (short)f2bf(p3);                     \
    }                                                                         \
    asm volatile("s_waitcnt lgkmcnt(0)" ::: "memory");                        \
    __builtin_amdgcn_sched_barrier(0);                                        \
    bf16x8 pa0 = *(const bf16x8*)&Plds[wid][lo][hi * 8];                      \
    bf16x8 pa1 = *(const bf16x8*)&Plds[wid][lo][32 + hi * 8];                 \
    accO[0] = __builtin_amdgcn_mfma_f32_16x16x32_bf16(pa0, vv0, accO[0], 0, 0, 0); \
    accO[0] = __builtin_amdgcn_mfma_f32_16x16x32_bf16(pa1, vv1, accO[0], 0, 0, 0); \
    accO[1] = __builtin_amdgcn_mfma_f32_16x16x32_bf16(pa0, vv2, accO[1], 0, 0, 0); \
    accO[1] = __builtin_amdgcn_mfma_f32_16x16x32_bf16(pa1, vv3, accO[1], 0, 0, 0); \
    accO[2] = __builtin_amdgcn_mfma_f32_16x16x32_bf16(pa0, vv4, accO[2], 0, 0, 0); \
    accO[2] = __builtin_amdgcn_mfma_f32_16x16x32_bf16(pa1, vv5, accO[2], 0, 0, 0); \
    accO[3] = __builtin_amdgcn_mfma_f32_16x16x32_bf16(pa0, vv6, accO[3], 0, 0, 0); \
    accO[3] = __builtin_amdgcn_mfma_f32_16x16x32_bf16(pa1, vv7, accO[3], 0, 0, 0); \
} while (0)

    LOADK(kA0,kA1,kA2,kA3,kA4,kA5,kA6,kA7, 0);
    for (int kt = 0; kt < 16; kt += 2) {
        BODY(kA0,kA1,kA2,kA3,kA4,kA5,kA6,kA7,
             kB0,kB1,kB2,kB3,kB4,kB5,kB6,kB7, kt);
        BODY(kB0,kB1,kB2,kB3,kB4,kB5,kB6,kB7,
             kA0,kA1,kA2,kA3,kA4,kA5,kA6,kA7, kt + 1);
    }
#undef BODY
#undef LOADV
#undef LOADK

#pragma unroll
    for (int r = 0; r < 4; r++) {
        float s = sump[r];
        s += __shfl_xor(s, 1, 64);
        s += __shfl_xor(s, 2, 64);
        s += __shfl_xor(s, 4, 64);
        s += __shfl_xor(s, 8, 64);
        sump[r] = 1.f / s;
    }
#pragma unroll
    for (int n = 0; n < 4; n++) {
        int d = n * 16 + lo;
#pragma unroll
        for (int r = 0; r < 4; r++) {
            int qrow = qrow0 + hi * 4 + r;
            AO[((size_t)(b * NN_ + qrow)) * CC + h * HDD + d] = f2bf(accO[n][r] * sump[r]);
        }
    }
}

// ---------------------------------------------------------------- proj GEMM
__global__ __launch_bounds__(256)
void proj_gemm(const unsigned short* __restrict__ A,
               const unsigned short* __restrict__ Bt,
               const float* __restrict__ bias,
               float* __restrict__ Out) {
    __shared__ short sA[128 * 32];
    __shared__ short sB[128 * 32];
    const int K = 768;
    const int lane = threadIdx.x & 63;
    const int wid  = threadIdx.x >> 6;
    const int wr = wid >> 1, wc = wid & 1;
    const int brow = blockIdx.x * 128;
    const int bcol = blockIdx.y * 128;
    const int t = threadIdx.x;

    f32x4 acc[4][4];
#pragma unroll
    for (int m = 0; m < 4; m++)
#pragma unroll
        for (int n = 0; n < 4; n++) acc[m][n] = (f32x4){0.f, 0.f, 0.f, 0.f};

    for (int k0 = 0; k0 < K; k0 += 32) {
#pragma unroll
        for (int i = 0; i < 2; i++) {
            int tt  = i * 256 + t;
            int row = tt >> 2;
            int kc  = (tt & 3) * 8;
            const unsigned short* ga = A  + (size_t)(brow + row) * K + k0 + kc;
            const unsigned short* gb = Bt + (size_t)(bcol + row) * K + k0 + kc;
            short* la = &sA[(i * 256 + wid * 64) * 8];
            short* lb = &sB[(i * 256 + wid * 64) * 8];
            __builtin_amdgcn_global_load_lds((const __attribute__((address_space(1))) void*)ga,
                                             (__attribute__((address_space(3))) void*)la, 16, 0, 0);
            __builtin_amdgcn_global_load_lds((const __attribute__((address_space(1))) void*)gb,
                                             (__attribute__((address_space(3))) void*)lb, 16, 0, 0);
        }
        __syncthreads();
        bf16x8 af[4], bfg[4];
#pragma unroll
        for (int m = 0; m < 4; m++) {
            int r = wr * 64 + m * 16 + (lane & 15);
            af[m] = *(const bf16x8*)&sA[r * 32 + (lane >> 4) * 8];
        }
#pragma unroll
        for (int n = 0; n < 4; n++) {
            int c = wc * 64 + n * 16 + (lane & 15);
            bfg[n] = *(const bf16x8*)&sB[c * 32 + (lane >> 4) * 8];
        }
#pragma unroll
        for (int m = 0; m < 4; m++)
#pragma unroll
            for (int n = 0; n < 4; n++)
                acc[m][n] = __builtin_amdgcn_mfma_f32_16x16x32_bf16(af[m], bfg[n], acc[m][n], 0, 0, 0);
        __syncthreads();
    }
#pragma unroll
    for (int m = 0; m < 4; m++)
#pragma unroll
        for (int n = 0; n < 4; n++) {
            int col = bcol + wc * 64 + n * 16 + (lane & 15);
            float bv = bias[col];
#pragma unroll
            for (int r = 0; r < 4; r++) {
                int row = brow + wr * 64 + m * 16 + (lane >> 4) * 4 + r;
                Out[(size_t)row * 768 + col] = acc[m][n][r] + bv;
            }
        }
}

// ---------------------------------------------------------------- launcher
extern "C" void kernel_launch(void* const* d_in, const int* in_sizes, int n_in,
                              void* d_out, int out_size, void* d_ws, size_t ws_size,
                              hipStream_t stream) {
    const float* x     = (const float*)d_in[0];
    const float* Wqkv  = (const float*)d_in[1];
    const float* Wfc1  = (const float*)d_in[2];
    const float* bfc1  = (const float*)d_in[3];
    const float* Wfc2  = (const float*)d_in[4];
    const float* bfc2  = (const float*)d_in[5];
    const float* Wproj = (const float*)d_in[6];
    const float* bproj = (const float*)d_in[7];
    float* out = (float*)d_out;

    char* ws = (char*)d_ws;
    const size_t SZ_XN = (size_t)8192 * 768 * 2;                 // 12.58 MB
    unsigned short* x_bf    = (unsigned short*)ws; ws += SZ_XN;  // reused as attn_out
    unsigned short* wqkv_bf = (unsigned short*)ws; ws += (size_t)2304 * 768 * 2;
    unsigned short* wproj_bf= (unsigned short*)ws; ws += (size_t)768 * 768 * 2;
    unsigned short* wfc1_bf = (unsigned short*)ws; ws += 64 * 64 * 2;
    unsigned short* wfc2_bf = (unsigned short*)ws; ws += 64 * 64 * 2;
    unsigned short* Rq      = (unsigned short*)ws; ws += SZ_XN;  // -> Q_spk (in place)
    unsigned short* Rk      = (unsigned short*)ws; ws += SZ_XN;  // -> K_spk (in place)
    unsigned short* VT      = (unsigned short*)ws; ws += SZ_XN;  // V_rec transposed [b,h,d,n]

    cvt4_f32_bf16<<<2048, 256, 0, stream>>>((const f32x4v*)x,     (u16x4*)x_bf,     8192 * 768 / 4);
    cvt4_f32_bf16<<<1024, 256, 0, stream>>>((const f32x4v*)Wqkv,  (u16x4*)wqkv_bf,  2304 * 768 / 4);
    cvt4_f32_bf16<<<576,  256, 0, stream>>>((const f32x4v*)Wproj, (u16x4*)wproj_bf, 768 * 768 / 4);
    cvt4_f32_bf16<<<4,    256, 0, stream>>>((const f32x4v*)Wfc1,  (u16x4*)wfc1_bf,  64 * 64 / 4);
    cvt4_f32_bf16<<<4,    256, 0, stream>>>((const f32x4v*)Wfc2,  (u16x4*)wfc2_bf,  64 * 64 / 4);

    qkv_gemm<<<dim3(64, 18), 256, 0, stream>>>(x_bf, wqkv_bf, Rq, Rk, VT);
    spk_kernel<<<1536, 256, 0, stream>>>(Rq, wfc1_bf, bfc1);
    spk_kernel<<<1536, 256, 0, stream>>>(Rk, wfc2_bf, bfc2);
    attn_kernel<<<1536, 256, 0, stream>>>(Rq, Rk, VT, x_bf);
    proj_gemm<<<dim3(64, 6), 256, 0, stream>>>(x_bf, wproj_bf, bproj, out);
}

// Round 3
// 164.659 us; speedup vs baseline: 1.8188x; 1.7336x over previous
//
#include <hip/hip_runtime.h>
#include <hip/hip_bf16.h>
#include <stdint.h>
#include <math.h>

// Sizes fixed by the problem.
#define BB   8
#define NN_  1024
#define CC   768
#define HH   12
#define HDD  64

typedef __attribute__((ext_vector_type(8))) short bf16x8;   // 8 bf16 (4 VGPRs)
typedef __attribute__((ext_vector_type(4))) float f32x4;    // 16x16 MFMA acc
typedef __attribute__((ext_vector_type(16))) float f32x16;  // 32x32 MFMA acc
typedef __attribute__((ext_vector_type(4))) float f32x4v;
typedef __attribute__((ext_vector_type(4))) unsigned short u16x4;

union FragU { unsigned int u[4]; bf16x8 b; };

__device__ __forceinline__ unsigned short f2bf(float f) {
    union { float f; unsigned int u; } v; v.f = f;
    unsigned int r = v.u + 0x7fffu + ((v.u >> 16) & 1u);   // RNE
    return (unsigned short)(r >> 16);
}

#define CVTPK(d_, a_, b_) asm("v_cvt_pk_bf16_f32 %0, %1, %2" : "=v"(d_) : "v"(a_), "v"(b_))
// v_permlane32_swap_b32: vdst.high-row <-> vsrc.low-row
#define SWAP32(a_, b_) asm("v_permlane32_swap_b32 %0, %1" : "+v"(a_), "+v"(b_))

// ---------------------------------------------------------------- converts
__global__ void cvt4_f32_bf16(const f32x4v* __restrict__ in,
                              u16x4* __restrict__ out, int n4) {
    int i = blockIdx.x * blockDim.x + threadIdx.x;
    int stride = gridDim.x * blockDim.x;
    for (; i < n4; i += stride) {
        f32x4v v = in[i];
        u16x4 o;
        o.x = f2bf(v.x); o.y = f2bf(v.y); o.z = f2bf(v.z); o.w = f2bf(v.w);
        out[i] = o;
    }
}

// ---------------------------------------------------------------- QKV GEMM
__global__ __launch_bounds__(256)
void qkv_gemm(const unsigned short* __restrict__ A,
              const unsigned short* __restrict__ Bt,
              unsigned short* __restrict__ Rq,
              unsigned short* __restrict__ Rk,
              unsigned short* __restrict__ VT) {
    __shared__ short sA[128 * 32];
    __shared__ short sB[128 * 32];
    const int K = 768;
    const int lane = threadIdx.x & 63;
    const int wid  = threadIdx.x >> 6;
    const int wr = wid >> 1, wc = wid & 1;
    const int brow = blockIdx.x * 128;
    const int bcol = blockIdx.y * 128;
    const int t = threadIdx.x;

    f32x4 acc[4][4];
#pragma unroll
    for (int m = 0; m < 4; m++)
#pragma unroll
        for (int n = 0; n < 4; n++) acc[m][n] = (f32x4){0.f, 0.f, 0.f, 0.f};

    for (int k0 = 0; k0 < K; k0 += 32) {
#pragma unroll
        for (int i = 0; i < 2; i++) {
            int tt  = i * 256 + t;          // 0..511
            int row = tt >> 2;
            int kc  = (tt & 3) * 8;
            const unsigned short* ga = A  + (size_t)(brow + row) * K + k0 + kc;
            const unsigned short* gb = Bt + (size_t)(bcol + row) * K + k0 + kc;
            short* la = &sA[(i * 256 + wid * 64) * 8];   // wave-uniform base
            short* lb = &sB[(i * 256 + wid * 64) * 8];
            __builtin_amdgcn_global_load_lds((const __attribute__((address_space(1))) void*)ga,
                                             (__attribute__((address_space(3))) void*)la, 16, 0, 0);
            __builtin_amdgcn_global_load_lds((const __attribute__((address_space(1))) void*)gb,
                                             (__attribute__((address_space(3))) void*)lb, 16, 0, 0);
        }
        __syncthreads();
        bf16x8 af[4], bfg[4];
#pragma unroll
        for (int m = 0; m < 4; m++) {
            int r = wr * 64 + m * 16 + (lane & 15);
            af[m] = *(const bf16x8*)&sA[r * 32 + (lane >> 4) * 8];
        }
#pragma unroll
        for (int n = 0; n < 4; n++) {
            int c = wc * 64 + n * 16 + (lane & 15);
            bfg[n] = *(const bf16x8*)&sB[c * 32 + (lane >> 4) * 8];
        }
#pragma unroll
        for (int m = 0; m < 4; m++)
#pragma unroll
            for (int n = 0; n < 4; n++)
                acc[m][n] = __builtin_amdgcn_mfma_f32_16x16x32_bf16(af[m], bfg[n], acc[m][n], 0, 0, 0);
        __syncthreads();
    }

    const int colbase = bcol + wc * 64;
    const int p  = colbase / 768;
    const int hh = (colbase - p * 768) >> 6;
    const int rowbase = brow + wr * 64;
    const int bb = rowbase >> 10;
    const size_t qk_base = ((size_t)(bb * HH + hh)) * NN_ * HDD;
    const size_t vt_base = ((size_t)(bb * HH + hh)) * HDD * NN_;
#pragma unroll
    for (int m = 0; m < 4; m++) {
        int nn = (rowbase + m * 16 + (lane >> 4) * 4) & (NN_ - 1);
#pragma unroll
        for (int n = 0; n < 4; n++) {
            int dd = n * 16 + (lane & 15);
#pragma unroll
            for (int r = 0; r < 4; r++) {
                float rl = fmaxf(acc[m][n][r], 0.f);
                if (p == 0)      Rq[qk_base + (size_t)(nn + r) * HDD + dd] = f2bf(rl);
                else if (p == 1) Rk[qk_base + (size_t)(nn + r) * HDD + dd] = f2bf(rl);
                else             VT[vt_base + (size_t)dd * NN_ + (nn + r)] = f2bf(4.f * rl);
            }
        }
    }
}

// ---------------------------------------------------------------- spk FC
__global__ __launch_bounds__(256)
void spk_kernel(unsigned short* __restrict__ R,
                const unsigned short* __restrict__ W,
                const float* __restrict__ bias) {
    const int lane = threadIdx.x & 63;
    const int wid  = threadIdx.x >> 6;
    const int rowbase = blockIdx.x * 64 + wid * 16;
    const unsigned short* Arow = R + (size_t)(rowbase + (lane & 15)) * 64 + (lane >> 4) * 8;
    bf16x8 a0 = *(const bf16x8*)Arow;
    bf16x8 a1 = *(const bf16x8*)(Arow + 32);
    f32x4 acc[4];
#pragma unroll
    for (int n = 0; n < 4; n++) {
        acc[n] = (f32x4){0.f, 0.f, 0.f, 0.f};
        const unsigned short* Wrow = W + (size_t)(n * 16 + (lane & 15)) * 64 + (lane >> 4) * 8;
        bf16x8 b0 = *(const bf16x8*)Wrow;
        bf16x8 b1 = *(const bf16x8*)(Wrow + 32);
        acc[n] = __builtin_amdgcn_mfma_f32_16x16x32_bf16(a0, b0, acc[n], 0, 0, 0);
        acc[n] = __builtin_amdgcn_mfma_f32_16x16x32_bf16(a1, b1, acc[n], 0, 0, 0);
    }
#pragma unroll
    for (int n = 0; n < 4; n++) {
        int col = n * 16 + (lane & 15);
        float bv = bias[col];
#pragma unroll
        for (int r = 0; r < 4; r++) {
            int row = rowbase + (lane >> 4) * 4 + r;
            R[(size_t)row * 64 + col] = f2bf(acc[n][r] + bv);
        }
    }
}

// ---------------------------------------------------------------- attention
// m214-style: S~ = K.Q^T via 32x32x16 MFMA (swapped operands) so each lane
// owns P[k-set][q=lane&31] lane-locally. Softmax in registers; PV A-frags
// built with v_cvt_pk_bf16_f32 + v_permlane32_swap_b32 (no P LDS roundtrip).
// K,V tiles staged to LDS once per block via global_load_lds, double-buffered,
// XOR-swizzled (pre-swizzled global source + swizzled reads; rule #21).
__global__ __launch_bounds__(256, 2)
void attn_kernel(const unsigned short* __restrict__ Q,
                 const unsigned short* __restrict__ Kx,
                 const unsigned short* __restrict__ VT,
                 unsigned short* __restrict__ AO) {
    __shared__ short sK[2][64 * 64];
    __shared__ short sV[2][64 * 64];
    __shared__ float sinv[4][32];

    const int t    = threadIdx.x;
    const int lane = t & 63;
    const int wid  = t >> 6;
    const int l31  = lane & 31;
    const int hi5  = lane >> 5;

    // XCD swizzle: 8 q-tiles of one head land on one XCD (768 = 8*96, bijective)
    const int bid = (int)blockIdx.x;
    const int lbid = (bid & 7) * 96 + (bid >> 3);
    const int bh = lbid >> 3;          // 0..95
    const int qt = lbid & 7;           // 0..7
    const int b = bh / HH, h = bh - b * HH;

    const unsigned short* Qs = Q  + (size_t)bh * NN_ * HDD;
    const unsigned short* Ks = Kx + (size_t)bh * NN_ * HDD;
    const unsigned short* Vt = VT + (size_t)bh * HDD * NN_;
    const int q0 = qt * 128 + wid * 32;

    // Q B-frags: B[col=q=lane&31][kc = ds*16 + hi5*8 + j]
    bf16x8 qf[4];
#pragma unroll
    for (int ds = 0; ds < 4; ds++)
        qf[ds] = *(const bf16x8*)&Qs[(size_t)(q0 + l31) * HDD + ds * 16 + hi5 * 8];

    f32x16 O0, O1;
#pragma unroll
    for (int r = 0; r < 16; r++) { O0[r] = 0.f; O1[r] = 0.f; }
    float sumacc = 0.f;

    // staging: thread t, round i covers linear slot li = i*256+t of the 8KB tile.
    // LDS[row][slot] = G[row][slot ^ (row&7)]  (16B slots, 64 rows of 128B)
    const int srow = t >> 3;           // rounds add 32
    const int sslot = t & 7;
    const int dstoff = ((t & 192)) * 8;  // wave-uniform base (shorts), rounds add 256*8

#define STAGE(buf_, kt_) do {                                                  \
    _Pragma("unroll")                                                          \
    for (int i = 0; i < 2; i++) {                                              \
        int row_ = srow + i * 32;                                              \
        int sl_  = (sslot ^ (row_ & 7)) << 3;                                  \
        const unsigned short* gk_ = Ks + (size_t)((kt_) * 64 + row_) * HDD + sl_; \
        const unsigned short* gv_ = Vt + (size_t)row_ * NN_ + (kt_) * 64 + sl_;   \
        short* dk_ = &sK[buf_][i * 2048 + dstoff];                             \
        short* dv_ = &sV[buf_][i * 2048 + dstoff];                             \
        __builtin_amdgcn_global_load_lds((const __attribute__((address_space(1))) void*)gk_, \
                                         (__attribute__((address_space(3))) void*)dk_, 16, 0, 0); \
        __builtin_amdgcn_global_load_lds((const __attribute__((address_space(1))) void*)gv_, \
                                         (__attribute__((address_space(3))) void*)dv_, 16, 0, 0); \
    }                                                                          \
} while (0)

    // builds two PV A-frags (16-k subtiles) from 16 lane-local p values
#define MKFRAGS(P_, F0_, F1_) do {                                             \
    unsigned int c0,c1,c2,c3,c4,c5,c6,c7;                                      \
    CVTPK(c0, P_[0],  P_[1]);  CVTPK(c1, P_[2],  P_[3]);                       \
    CVTPK(c2, P_[4],  P_[5]);  CVTPK(c3, P_[6],  P_[7]);                       \
    CVTPK(c4, P_[8],  P_[9]);  CVTPK(c5, P_[10], P_[11]);                      \
    CVTPK(c6, P_[12], P_[13]); CVTPK(c7, P_[14], P_[15]);                      \
    SWAP32(c0, c2); SWAP32(c1, c3); SWAP32(c4, c6); SWAP32(c5, c7);            \
    FragU fu0_, fu1_;                                                          \
    fu0_.u[0]=c0; fu0_.u[1]=c1; fu0_.u[2]=c2; fu0_.u[3]=c3;                    \
    fu1_.u[0]=c4; fu1_.u[1]=c5; fu1_.u[2]=c6; fu1_.u[3]=c7;                    \
    F0_ = fu0_.b; F1_ = fu1_.b;                                                \
} while (0)

    STAGE(0, 0);
    __syncthreads();

    int buf = 0;
    for (int kt = 0; kt < 16; ++kt) {
        if (kt < 15) STAGE(buf ^ 1, kt + 1);

        const char* kbase = (const char*)&sK[buf][0];
        const char* vbase = (const char*)&sV[buf][0];

        // V B-frags: B[col=d][kc = ks*16 + hi5*8 + j], swizzled read
        bf16x8 vbf[4][2];
#pragma unroll
        for (int ks = 0; ks < 4; ks++)
#pragma unroll
            for (int dt = 0; dt < 2; dt++) {
                int d = dt * 32 + l31;
                vbf[ks][dt] = *(const bf16x8*)(vbase + d * 128 +
                               ((ks * 32 + hi5 * 16) ^ ((d & 7) << 4)));
            }
        // K A-frags: A[row=k][kc = ds*16 + hi5*8 + j]
        bf16x8 ka[2][4];
#pragma unroll
        for (int kt2 = 0; kt2 < 2; kt2++)
#pragma unroll
            for (int ds = 0; ds < 4; ds++) {
                int kk = kt2 * 32 + l31;
                ka[kt2][ds] = *(const bf16x8*)(kbase + kk * 128 +
                               ((ds * 32 + hi5 * 16) ^ ((kk & 7) << 4)));
            }

        f32x16 S0, S1;
#pragma unroll
        for (int r = 0; r < 16; r++) { S0[r] = 0.f; S1[r] = 0.f; }
#pragma unroll
        for (int ds = 0; ds < 4; ds++) {
            S0 = __builtin_amdgcn_mfma_f32_32x32x16_bf16(ka[0][ds], qf[ds], S0, 0, 0, 0);
            S1 = __builtin_amdgcn_mfma_f32_32x32x16_bf16(ka[1][ds], qf[ds], S1, 0, 0, 0);
        }

        // p = exp(0.25*relu(S)) = 2^(0.36067376*relu(S)); lane-local softmax numerators
        float p0[16], p1[16];
#pragma unroll
        for (int r = 0; r < 16; r++) {
            p0[r] = exp2f(0.36067376f * fmaxf(S0[r], 0.f));
            p1[r] = exp2f(0.36067376f * fmaxf(S1[r], 0.f));
        }
        float s0 = 0.f, s1 = 0.f;
#pragma unroll
        for (int r = 0; r < 16; r++) { s0 += p0[r]; s1 += p1[r]; }
        sumacc += s0 + s1;

        bf16x8 paf0, paf1, paf2, paf3;
        MKFRAGS(p0, paf0, paf1);
        MKFRAGS(p1, paf2, paf3);

        O0 = __builtin_amdgcn_mfma_f32_32x32x16_bf16(paf0, vbf[0][0], O0, 0, 0, 0);
        O1 = __builtin_amdgcn_mfma_f32_32x32x16_bf16(paf0, vbf[0][1], O1, 0, 0, 0);
        O0 = __builtin_amdgcn_mfma_f32_32x32x16_bf16(paf1, vbf[1][0], O0, 0, 0, 0);
        O1 = __builtin_amdgcn_mfma_f32_32x32x16_bf16(paf1, vbf[1][1], O1, 0, 0, 0);
        O0 = __builtin_amdgcn_mfma_f32_32x32x16_bf16(paf2, vbf[2][0], O0, 0, 0, 0);
        O1 = __builtin_amdgcn_mfma_f32_32x32x16_bf16(paf2, vbf[2][1], O1, 0, 0, 0);
        O0 = __builtin_amdgcn_mfma_f32_32x32x16_bf16(paf3, vbf[3][0], O0, 0, 0, 0);
        O1 = __builtin_amdgcn_mfma_f32_32x32x16_bf16(paf3, vbf[3][1], O1, 0, 0, 0);

        __syncthreads();   // drains staging vmcnt + protects buffer reuse
        buf ^= 1;
    }
#undef STAGE
#undef MKFRAGS

    // full row-sum: this lane's half + partner half (lane^32), per q=lane&31
    float stot = sumacc + __shfl_xor(sumacc, 32, 64);
    float inv = 1.f / stot;
    if (l31 == lane) sinv[wid][l31] = inv;   // lanes 0..31 write
    __syncthreads();

#pragma unroll
    for (int r = 0; r < 16; r++) {
        int qloc = (r & 3) + 8 * (r >> 2) + 4 * hi5;
        float iv = sinv[wid][qloc];
        size_t row = (size_t)(b * NN_ + q0 + qloc) * CC + h * HDD;
        AO[row + l31]      = f2bf(O0[r] * iv);
        AO[row + 32 + l31] = f2bf(O1[r] * iv);
    }
}

// ---------------------------------------------------------------- proj GEMM
__global__ __launch_bounds__(256)
void proj_gemm(const unsigned short* __restrict__ A,
               const unsigned short* __restrict__ Bt,
               const float* __restrict__ bias,
               float* __restrict__ Out) {
    __shared__ short sA[128 * 32];
    __shared__ short sB[128 * 32];
    const int K = 768;
    const int lane = threadIdx.x & 63;
    const int wid  = threadIdx.x >> 6;
    const int wr = wid >> 1, wc = wid & 1;
    const int brow = blockIdx.x * 128;
    const int bcol = blockIdx.y * 128;
    const int t = threadIdx.x;

    f32x4 acc[4][4];
#pragma unroll
    for (int m = 0; m < 4; m++)
#pragma unroll
        for (int n = 0; n < 4; n++) acc[m][n] = (f32x4){0.f, 0.f, 0.f, 0.f};

    for (int k0 = 0; k0 < K; k0 += 32) {
#pragma unroll
        for (int i = 0; i < 2; i++) {
            int tt  = i * 256 + t;
            int row = tt >> 2;
            int kc  = (tt & 3) * 8;
            const unsigned short* ga = A  + (size_t)(brow + row) * K + k0 + kc;
            const unsigned short* gb = Bt + (size_t)(bcol + row) * K + k0 + kc;
            short* la = &sA[(i * 256 + wid * 64) * 8];
            short* lb = &sB[(i * 256 + wid * 64) * 8];
            __builtin_amdgcn_global_load_lds((const __attribute__((address_space(1))) void*)ga,
                                             (__attribute__((address_space(3))) void*)la, 16, 0, 0);
            __builtin_amdgcn_global_load_lds((const __attribute__((address_space(1))) void*)gb,
                                             (__attribute__((address_space(3))) void*)lb, 16, 0, 0);
        }
        __syncthreads();
        bf16x8 af[4], bfg[4];
#pragma unroll
        for (int m = 0; m < 4; m++) {
            int r = wr * 64 + m * 16 + (lane & 15);
            af[m] = *(const bf16x8*)&sA[r * 32 + (lane >> 4) * 8];
        }
#pragma unroll
        for (int n = 0; n < 4; n++) {
            int c = wc * 64 + n * 16 + (lane & 15);
            bfg[n] = *(const bf16x8*)&sB[c * 32 + (lane >> 4) * 8];
        }
#pragma unroll
        for (int m = 0; m < 4; m++)
#pragma unroll
            for (int n = 0; n < 4; n++)
                acc[m][n] = __builtin_amdgcn_mfma_f32_16x16x32_bf16(af[m], bfg[n], acc[m][n], 0, 0, 0);
        __syncthreads();
    }
#pragma unroll
    for (int m = 0; m < 4; m++)
#pragma unroll
        for (int n = 0; n < 4; n++) {
            int col = bcol + wc * 64 + n * 16 + (lane & 15);
            float bv = bias[col];
#pragma unroll
            for (int r = 0; r < 4; r++) {
                int row = brow + wr * 64 + m * 16 + (lane >> 4) * 4 + r;
                Out[(size_t)row * 768 + col] = acc[m][n][r] + bv;
            }
        }
}

// ---------------------------------------------------------------- launcher
extern "C" void kernel_launch(void* const* d_in, const int* in_sizes, int n_in,
                              void* d_out, int out_size, void* d_ws, size_t ws_size,
                              hipStream_t stream) {
    const float* x     = (const float*)d_in[0];
    const float* Wqkv  = (const float*)d_in[1];
    const float* Wfc1  = (const float*)d_in[2];
    const float* bfc1  = (const float*)d_in[3];
    const float* Wfc2  = (const float*)d_in[4];
    const float* bfc2  = (const float*)d_in[5];
    const float* Wproj = (const float*)d_in[6];
    const float* bproj = (const float*)d_in[7];
    float* out = (float*)d_out;

    char* ws = (char*)d_ws;
    const size_t SZ_XN = (size_t)8192 * 768 * 2;                 // 12.58 MB
    unsigned short* x_bf    = (unsigned short*)ws; ws += SZ_XN;  // reused as attn_out
    unsigned short* wqkv_bf = (unsigned short*)ws; ws += (size_t)2304 * 768 * 2;
    unsigned short* wproj_bf= (unsigned short*)ws; ws += (size_t)768 * 768 * 2;
    unsigned short* wfc1_bf = (unsigned short*)ws; ws += 64 * 64 * 2;
    unsigned short* wfc2_bf = (unsigned short*)ws; ws += 64 * 64 * 2;
    unsigned short* Rq      = (unsigned short*)ws; ws += SZ_XN;  // -> Q_spk (in place)
    unsigned short* Rk      = (unsigned short*)ws; ws += SZ_XN;  // -> K_spk (in place)
    unsigned short* VT      = (unsigned short*)ws; ws += SZ_XN;  // V_rec transposed [b,h,d,n]

    cvt4_f32_bf16<<<2048, 256, 0, stream>>>((const f32x4v*)x,     (u16x4*)x_bf,     8192 * 768 / 4);
    cvt4_f32_bf16<<<1024, 256, 0, stream>>>((const f32x4v*)Wqkv,  (u16x4*)wqkv_bf,  2304 * 768 / 4);
    cvt4_f32_bf16<<<576,  256, 0, stream>>>((const f32x4v*)Wproj, (u16x4*)wproj_bf, 768 * 768 / 4);
    cvt4_f32_bf16<<<4,    256, 0, stream>>>((const f32x4v*)Wfc1,  (u16x4*)wfc1_bf,  64 * 64 / 4);
    cvt4_f32_bf16<<<4,    256, 0, stream>>>((const f32x4v*)Wfc2,  (u16x4*)wfc2_bf,  64 * 64 / 4);

    qkv_gemm<<<dim3(64, 18), 256, 0, stream>>>(x_bf, wqkv_bf, Rq, Rk, VT);
    spk_kernel<<<1536, 256, 0, stream>>>(Rq, wfc1_bf, bfc1);
    spk_kernel<<<1536, 256, 0, stream>>>(Rk, wfc2_bf, bfc2);
    attn_kernel<<<768, 256, 0, stream>>>(Rq, Rk, VT, x_bf);
    proj_gemm<<<dim3(64, 6), 256, 0, stream>>>(x_bf, wproj_bf, bproj, out);
}